// Round 1
// baseline (1649.419 us; speedup 1.0000x reference)
//
#include <hip/hip_runtime.h>
#include <stdint.h>

#define BQ 128      // batch
#define DF 512      // feature dim
#define MM 262144   // memory slots
#define TOPK 256
#define CAP 4096    // candidate capacity per row

// ---------- float <-> order-preserving uint32 key ----------
__device__ __forceinline__ uint32_t f2key(float f) {
    uint32_t b = __float_as_uint(f);
    return (b & 0x80000000u) ? ~b : (b | 0x80000000u);
}
__device__ __forceinline__ float key2f(uint32_t k) {
    uint32_t b = (k & 0x80000000u) ? (k ^ 0x80000000u) : ~k;
    return __uint_as_float(b);
}

// ---------- 1. normalize query rows, write transposed qT[d][b] ----------
__global__ void norm_q(const float* __restrict__ q, float* __restrict__ qT) {
    int b = blockIdx.x;      // 128 blocks
    int t = threadIdx.x;     // 256 threads
    __shared__ float red[256];
    float v0 = q[b * DF + t];
    float v1 = q[b * DF + t + 256];
    red[t] = v0 * v0 + v1 * v1;
    __syncthreads();
    for (int o = 128; o > 0; o >>= 1) {
        if (t < o) red[t] += red[t + o];
        __syncthreads();
    }
    float inv = 1.0f / sqrtf(red[0]);
    qT[(size_t)t * BQ + b] = v0 * inv;
    qT[(size_t)(t + 256) * BQ + b] = v1 * inv;
}

// ---------- zero helper ----------
__global__ void zero32(uint32_t* __restrict__ p, int n) {
    int i = blockIdx.x * 256 + threadIdx.x;
    if (i < n) p[i] = 0;
}

// ---------- 2. fp32 score GEMM: scores[b][m] = sum_d qn[b][d]*key[m][d] ----------
#define TM 64    // key rows per block
#define DC 128   // d-chunk staged in LDS
__global__ __launch_bounds__(256) void gemm_scores(const float* __restrict__ key,
                                                   const float* __restrict__ qT,
                                                   float* __restrict__ scores) {
    __shared__ float kt[DC * 65];  // [d][m], stride 65 kills bank conflicts
    int t = threadIdx.x;
    int m0 = blockIdx.x * TM;
    int lane = t & 63;                       // key row within tile
    int qb = (t >> 6) * 32;                  // b-group base (wave-uniform)
    qb = __builtin_amdgcn_readfirstlane(qb);

    float acc[32];
#pragma unroll
    for (int j = 0; j < 32; j++) acc[j] = 0.f;

    for (int dc = 0; dc < DF; dc += DC) {
        __syncthreads();
        // stage 64 rows x 128 d = 8192 floats; 32 per thread, coalesced reads
#pragma unroll
        for (int i = 0; i < 32; i++) {
            int linear = t + i * 256;
            int m = linear >> 7;       // /128
            int d = linear & 127;
            kt[d * 65 + m] = key[(size_t)(m0 + m) * DF + dc + d];
        }
        __syncthreads();
#pragma unroll 8
        for (int d = 0; d < DC; d++) {
            float kv = kt[d * 65 + lane];
            const float* qrow = qT + (size_t)(dc + d) * BQ + qb;  // wave-uniform -> s_load
#pragma unroll
            for (int j = 0; j < 32; j++) acc[j] += kv * qrow[j];
        }
    }
#pragma unroll
    for (int j = 0; j < 32; j++) {
        scores[(size_t)(qb + j) * MM + m0 + lane] = acc[j];
    }
}

// ---------- 3a. histogram passes (pass0: key>>24 ; pass1: next 8 bits within bin1) ----------
__global__ void hist_pass(const float* __restrict__ scores, uint32_t* __restrict__ hist,
                          const uint32_t* __restrict__ bin1, int pass) {
    __shared__ uint32_t h[256];
    int t = threadIdx.x;
    int row = blockIdx.y;
    h[t] = 0;
    __syncthreads();
    const float* srow = scores + (size_t)row * MM;
    int base = blockIdx.x * (MM / 32);
    uint32_t want = pass ? bin1[row] : 0;
    for (int i = 0; i < (MM / 32); i += 256) {
        uint32_t k = f2key(srow[base + i + t]);
        if (pass == 0)
            atomicAdd(&h[k >> 24], 1u);
        else if ((k >> 24) == want)
            atomicAdd(&h[(k >> 16) & 255u], 1u);
    }
    __syncthreads();
    if (h[t]) atomicAdd(&hist[row * 256 + t], h[t]);
}

// ---------- 3b. suffix-scan of a 256-bin histogram; pick boundary bin ----------
__global__ void scan_pass(const uint32_t* __restrict__ hist, uint32_t* __restrict__ outBin,
                          uint32_t* __restrict__ outCntGt, const uint32_t* __restrict__ cntGt1,
                          const uint32_t* __restrict__ bin1Arr, uint32_t* __restrict__ thr16,
                          int pass) {
    __shared__ uint32_t s[256];
    int row = blockIdx.x;
    int t = threadIdx.x;
    s[t] = hist[row * 256 + t];
    __syncthreads();
    for (int o = 1; o < 256; o <<= 1) {
        uint32_t v = s[t];
        uint32_t add = (t + o < 256) ? s[t + o] : 0;
        __syncthreads();
        s[t] = v + add;
        __syncthreads();
    }
    uint32_t need = pass ? (uint32_t)TOPK - cntGt1[row] : (uint32_t)TOPK;
    uint32_t sf = s[t];
    uint32_t sfn = (t < 255) ? s[t + 1] : 0;
    if (sf >= need && sfn < need) {   // unique boundary bin
        if (pass == 0) {
            outBin[row] = (uint32_t)t;
            outCntGt[row] = sfn;
        } else {
            thr16[row] = (bin1Arr[row] << 8) | (uint32_t)t;
        }
    }
}

// ---------- 3c. collect candidates with key16 >= threshold ----------
__global__ void collect(const float* __restrict__ scores, const uint32_t* __restrict__ thr16,
                        uint32_t* __restrict__ cnt, uint64_t* __restrict__ cand) {
    int row = blockIdx.y;
    int base = blockIdx.x * (MM / 32);
    uint32_t thr = thr16[row];
    const float* srow = scores + (size_t)row * MM;
    for (int i = 0; i < MM / 32; i += 256) {
        int m = base + i + threadIdx.x;
        uint32_t k = f2key(srow[m]);
        if ((k >> 16) >= thr) {
            uint32_t p = atomicAdd(&cnt[row], 1u);
            if (p < CAP) cand[(size_t)row * CAP + p] = ((uint64_t)k << 32) | (uint32_t)(~(uint32_t)m);
        }
    }
}

// ---------- 3d. bitonic sort candidates (desc score, asc index) + emit ----------
__global__ __launch_bounds__(1024) void sort_out(const uint64_t* __restrict__ cand,
                                                 const uint32_t* __restrict__ cnt,
                                                 float* __restrict__ outScore,
                                                 float* __restrict__ outIdx,
                                                 int* __restrict__ idxInt) {
    __shared__ uint64_t a[CAP];   // 32 KB
    int row = blockIdx.x;
    int t = threadIdx.x;
    uint32_t n = min(cnt[row], (uint32_t)CAP);
    for (int i = t; i < CAP; i += 1024) a[i] = (i < (int)n) ? cand[(size_t)row * CAP + i] : 0ull;
    __syncthreads();
    for (int k = 2; k <= CAP; k <<= 1) {
        for (int j = k >> 1; j > 0; j >>= 1) {
            for (int i = t; i < CAP; i += 1024) {
                int p = i ^ j;
                if (p > i) {
                    uint64_t x = a[i], y = a[p];
                    bool descBlock = ((i & k) == 0);
                    bool doswap = descBlock ? (x < y) : (x > y);
                    if (doswap) { a[i] = y; a[p] = x; }
                }
            }
            __syncthreads();
        }
    }
    if (t < TOPK) {
        uint64_t v = a[t];
        uint32_t k32 = (uint32_t)(v >> 32);
        uint32_t m = ~((uint32_t)v);
        outScore[row * TOPK + t] = key2f(k32);
        outIdx[row * TOPK + t] = (float)m;
        idxInt[row * TOPK + t] = (int)m;
    }
}

// ---------- 4. gather color_value rows ----------
__global__ void gather_feat(const float* __restrict__ cv, const int* __restrict__ idxInt,
                            float* __restrict__ outFeat) {
    int blk = blockIdx.x;  // 0..32767 = row*256 + k
    int m = idxInt[blk];
    const float4* src = (const float4*)(cv + (size_t)m * DF);
    float4* dst = (float4*)(outFeat + (size_t)blk * DF);
    dst[threadIdx.x] = src[threadIdx.x];  // 128 threads x float4 = 512 floats
}

extern "C" void kernel_launch(void* const* d_in, const int* in_sizes, int n_in,
                              void* d_out, int out_size, void* d_ws, size_t ws_size,
                              hipStream_t stream) {
    const float* query = (const float*)d_in[0];        // [128,512]
    const float* spatial_key = (const float*)d_in[1];  // [262144,512]
    const float* color_value = (const float*)d_in[2];  // [262144,512]

    // workspace layout (byte offsets, 256-aligned)
    char* ws = (char*)d_ws;
    size_t off = 0;
    auto alloc = [&](size_t bytes) { size_t o = off; off = (off + bytes + 255) & ~(size_t)255; return o; };
    size_t o_qT     = alloc((size_t)DF * BQ * 4);          // 256 KB
    size_t o_scores = alloc((size_t)BQ * MM * 4);          // 128 MB
    size_t o_hist1  = alloc((size_t)BQ * 256 * 4);
    size_t o_hist2  = alloc((size_t)BQ * 256 * 4);
    size_t o_bin1   = alloc((size_t)BQ * 4);
    size_t o_cntgt  = alloc((size_t)BQ * 4);
    size_t o_thr16  = alloc((size_t)BQ * 4);
    size_t o_cnt    = alloc((size_t)BQ * 4);
    size_t o_cand   = alloc((size_t)BQ * CAP * 8);         // 4 MB
    size_t o_idxI   = alloc((size_t)BQ * TOPK * 4);

    float*    qT     = (float*)(ws + o_qT);
    float*    scores = (float*)(ws + o_scores);
    uint32_t* hist1  = (uint32_t*)(ws + o_hist1);
    uint32_t* hist2  = (uint32_t*)(ws + o_hist2);
    uint32_t* bin1   = (uint32_t*)(ws + o_bin1);
    uint32_t* cntgt  = (uint32_t*)(ws + o_cntgt);
    uint32_t* thr16  = (uint32_t*)(ws + o_thr16);
    uint32_t* cnt    = (uint32_t*)(ws + o_cnt);
    uint64_t* cand   = (uint64_t*)(ws + o_cand);
    int*      idxI   = (int*)(ws + o_idxI);

    float* outFeat  = (float*)d_out;                            // [128,256,512]
    float* outScore = outFeat + (size_t)BQ * TOPK * DF;         // [128,256]
    float* outIdx   = outScore + (size_t)BQ * TOPK;             // [128,256] as float

    // 1. normalize + transpose query
    hipLaunchKernelGGL(norm_q, dim3(BQ), dim3(256), 0, stream, query, qT);

    // zero hist1, hist2, cnt (contiguous-ish: zero each region)
    hipLaunchKernelGGL(zero32, dim3((BQ * 256 + 255) / 256), dim3(256), 0, stream, hist1, BQ * 256);
    hipLaunchKernelGGL(zero32, dim3((BQ * 256 + 255) / 256), dim3(256), 0, stream, hist2, BQ * 256);
    hipLaunchKernelGGL(zero32, dim3(1), dim3(256), 0, stream, cnt, BQ);

    // 2. score GEMM
    hipLaunchKernelGGL(gemm_scores, dim3(MM / TM), dim3(256), 0, stream, spatial_key, qT, scores);

    // 3. radix-select top-256 per row
    hipLaunchKernelGGL(hist_pass, dim3(32, BQ), dim3(256), 0, stream, scores, hist1, bin1, 0);
    hipLaunchKernelGGL(scan_pass, dim3(BQ), dim3(256), 0, stream, hist1, bin1, cntgt, cntgt, bin1, thr16, 0);
    hipLaunchKernelGGL(hist_pass, dim3(32, BQ), dim3(256), 0, stream, scores, hist2, bin1, 1);
    hipLaunchKernelGGL(scan_pass, dim3(BQ), dim3(256), 0, stream, hist2, bin1, cntgt, cntgt, bin1, thr16, 1);
    hipLaunchKernelGGL(collect, dim3(32, BQ), dim3(256), 0, stream, scores, thr16, cnt, cand);
    hipLaunchKernelGGL(sort_out, dim3(BQ), dim3(1024), 0, stream, cand, cnt, outScore, outIdx, idxI);

    // 4. gather
    hipLaunchKernelGGL(gather_feat, dim3(BQ * TOPK), dim3(128), 0, stream, color_value, idxI, outFeat);
}